// Round 9
// baseline (542.135 us; speedup 1.0000x reference)
//
#include <hip/hip_runtime.h>

// ---------------------------------------------------------------------------
// SelfCrossAttention: B=4, T=1024+1024, d=512, H=8, hd=64. fp32 I/O,
// bf16 MFMA internals.
// prep (X->bf16; W_self/W_cross -> wt[n][k], q section pre-scaled by
//       0.125*log2(e); W_proj -> wtp[n][k])
//   -> qkv (128x128 glds GEMM; q/k computed TRANSPOSED via operand swap so
//           stores are b64-coalesced; V stored transposed+window-permuted)
//   -> attn (S^T flash, 64q/wave, 4-way key split; Q-tile in LDS (shared by
//            all 4 waves), VGPR forced <=128 for 4 waves/SIMD; exp2 softmax;
//            pairwise LDS tree merge of partials)
//   -> proj (glds GEMM, operand-swapped -> dwordx4 stores, tuple split).
// ---------------------------------------------------------------------------

typedef short     bf16x8 __attribute__((ext_vector_type(8)));
typedef short     bf16x4 __attribute__((ext_vector_type(4)));
typedef float     f32x4  __attribute__((ext_vector_type(4)));
typedef int       i32x4  __attribute__((ext_vector_type(4)));

#define DI __device__ __forceinline__

DI unsigned short f2b(float f) {            // fp32 -> bf16 bits, RNE-ish
    union { float f; unsigned int u; } x; x.f = f;
    unsigned int r = x.u + 0x7fffu + ((x.u >> 16) & 1u);
    return (unsigned short)(r >> 16);
}
DI unsigned int fbits(float f) { union { float f; unsigned int u; } x; x.f = f; return x.u; }
DI float bitsf(unsigned int u) { union { unsigned int u; float f; } x; x.u = u; return x.f; }
DI float b2f(unsigned short v) { return bitsf(((unsigned int)v) << 16); }

DI void glds16(const unsigned short* g, unsigned short* l) {   // 16B global->LDS
    __builtin_amdgcn_global_load_lds(
        (const __attribute__((address_space(1))) void*)g,
        (__attribute__((address_space(3))) void*)l, 16, 0, 0);
}

#define QSCALE 0.18033688011112042f   // 0.125 * log2(e): exp2-domain scores

// ---------------------------------------------------------------------------
// prep: [0,2048): X fp32 -> bf16 flat.
//       [2048,2432): W_self/W_cross -> wt[src][n][k], q-section * QSCALE
//       [2432,2496): W_proj -> wtp[n][k]
// ---------------------------------------------------------------------------
__global__ __launch_bounds__(256)
void prep_kernel(const float* __restrict__ Xs, const float* __restrict__ Xc,
                 const float* __restrict__ Ws, const float* __restrict__ Wc,
                 const float* __restrict__ Wp,
                 unsigned short* __restrict__ xb, unsigned short* __restrict__ wt,
                 unsigned short* __restrict__ wtp)
{
    const int bid = blockIdx.x, tid = threadIdx.x;
    if (bid < 2048) {
        int idx = bid * 2048 + tid * 8;
        const float* s = (idx < 2097152) ? (Xs + idx) : (Xc + idx - 2097152);
        f32x4 a0 = *(const f32x4*)s;
        f32x4 a1 = *(const f32x4*)(s + 4);
        bf16x8 v;
#pragma unroll
        for (int j = 0; j < 4; ++j) {
            ((unsigned short*)&v)[j]     = f2b(a0[j]);
            ((unsigned short*)&v)[4 + j] = f2b(a1[j]);
        }
        *(bf16x8*)(xb + idx) = v;
        return;
    }
    __shared__ unsigned short Tt[64 * 72];
    const float* W;
    unsigned short* dst;
    int k0, n0, ldn;
    float sc = 1.0f;
    if (bid < 2432) {
        int tj  = bid - 2048;
        int src = tj >= 192;  tj -= src * 192;
        k0  = (tj / 24) * 64;
        n0  = (tj % 24) * 64;
        W   = src ? Wc : Ws;
        ldn = 1536;
        dst = wt + (size_t)src * 786432;
        if (n0 < 512) sc = QSCALE;
    } else {
        int tj = bid - 2432;
        k0  = (tj >> 3) * 64;
        n0  = (tj & 7) * 64;
        W   = Wp;
        ldn = 512;
        dst = wtp;
    }
#pragma unroll
    for (int r = 0; r < 4; ++r) {
        int g  = tid + r * 256;
        int kr = g >> 4, nc4 = (g & 15) * 4;
        f32x4 v = *(const f32x4*)(W + (size_t)(k0 + kr) * ldn + n0 + nc4);
#pragma unroll
        for (int u = 0; u < 4; ++u)
            Tt[(nc4 + u) * 72 + kr] = f2b(v[u] * sc);
    }
    __syncthreads();
#pragma unroll
    for (int r = 0; r < 2; ++r) {
        int c = tid + r * 256;
        int nl = c >> 3, k8 = (c & 7) * 8;
        *(bf16x8*)(dst + (size_t)(n0 + nl) * 512 + k0 + k8) =
            *(const bf16x8*)(Tt + nl * 72 + k8);
    }
}

// ---------------------------------------------------------------------------
// QKV: xb @ wt^T + bias. 128x128 tile, glds staging. For q/k n-blocks the
// MFMA operands are SWAPPED (C comes out [n][t]) so each lane holds 4
// consecutive j at one t -> b64 stores. V blocks keep original orientation
// and store transposed+window-permuted (b64).
// ---------------------------------------------------------------------------
__global__ __launch_bounds__(256)
void qkv_kernel(const unsigned short* __restrict__ xb,
                const unsigned short* __restrict__ wt,
                const float* __restrict__ bs, const float* __restrict__ bc,
                unsigned short* __restrict__ qb, unsigned short* __restrict__ kb,
                unsigned short* __restrict__ vtb)
{
    const int src = blockIdx.z;
    const int m0 = blockIdx.x * 128, n0 = blockIdx.y * 128;
    const float* bias = src ? bc : bs;
    const unsigned short* X = xb + (size_t)src * 2097152;
    const unsigned short* W = wt + (size_t)src * 786432;

    __shared__ unsigned short As[128 * 32];
    __shared__ unsigned short Bs[128 * 32];

    const int tid = threadIdx.x, lane = tid & 63, w = tid >> 6;
    const int quad = lane >> 4, r16 = lane & 15;
    const int mrow = (w >> 1) * 64, ncol = (w & 1) * 64;
    const bool qk = (n0 < 1024);

    const f32x4 fz = {0.f, 0.f, 0.f, 0.f};
    f32x4 acc[4][4];
#pragma unroll
    for (int a = 0; a < 4; ++a)
#pragma unroll
        for (int b = 0; b < 4; ++b) acc[a][b] = fz;

    const int ci   = w << 1;
    const int rofs = lane >> 2, kofs = (lane & 3) * 8;
    const unsigned short* gA = X + (size_t)(m0 + ci * 16 + rofs) * 512 + kofs;
    const unsigned short* gB = W + (size_t)(n0 + ci * 16 + rofs) * 512 + kofs;
    unsigned short* lA = As + ci * 512 + lane * 8;
    unsigned short* lB = Bs + ci * 512 + lane * 8;

    for (int k0 = 0; k0 < 512; k0 += 32) {
        glds16(gA + k0, lA);
        glds16(gA + 16 * 512 + k0, lA + 512);
        glds16(gB + k0, lB);
        glds16(gB + 16 * 512 + k0, lB + 512);
        __syncthreads();

        bf16x8 af[4], bfr[4];
#pragma unroll
        for (int ms = 0; ms < 4; ++ms)
            af[ms] = *(const bf16x8*)(As + (mrow + ms * 16 + r16) * 32 + quad * 8);
#pragma unroll
        for (int ns = 0; ns < 4; ++ns)
            bfr[ns] = *(const bf16x8*)(Bs + (ncol + ns * 16 + r16) * 32 + quad * 8);
        if (qk) {
#pragma unroll
            for (int a = 0; a < 4; ++a)
#pragma unroll
                for (int b = 0; b < 4; ++b)
                    acc[a][b] = __builtin_amdgcn_mfma_f32_16x16x32_bf16(
                        bfr[a], af[b], acc[a][b], 0, 0, 0);   // C = [n][t]
        } else {
#pragma unroll
            for (int a = 0; a < 4; ++a)
#pragma unroll
                for (int b = 0; b < 4; ++b)
                    acc[a][b] = __builtin_amdgcn_mfma_f32_16x16x32_bf16(
                        af[a], bfr[b], acc[a][b], 0, 0, 0);   // C = [t][n]
        }
        __syncthreads();
    }

    if (qk) {
        const bool isq = (n0 < 512);
        unsigned short* dst = isq ? qb : kb;
        const float bsc = isq ? QSCALE : 1.0f;
#pragma unroll
        for (int ws = 0; ws < 4; ++ws) {
            int nb = n0 + ncol + ws * 16 + quad * 4;      // 4 consecutive n
            f32x4 bb = *(const f32x4*)(bias + nb);
            int col = nb & 511, hh = col >> 6, j0 = col & 63;
#pragma unroll
            for (int xs = 0; xs < 4; ++xs) {
                int mb = m0 + mrow + xs * 16 + r16;
                int bi = mb >> 10, tg = (mb & 1023) + (src << 10);
                bf16x4 pk;
#pragma unroll
                for (int i = 0; i < 4; ++i)
                    pk[i] = (short)f2b(acc[ws][xs][i] + bb[i] * bsc);
                *(bf16x4*)(dst + (((size_t)(bi * 8 + hh) * 2048 + tg) << 6) + j0) = pk;
            }
        }
    } else {
#pragma unroll
        for (int ms = 0; ms < 4; ++ms)
#pragma unroll
            for (int ns = 0; ns < 4; ++ns) {
                int n = n0 + ncol + ns * 16 + r16;
                int col = n & 511, hh = col >> 6, j = col & 63;
                float bb = bias[n];
                int mb = m0 + mrow + ms * 16 + quad * 4;
                int bi = mb >> 10, tg0 = (mb & 1023) + (src << 10);
                bf16x4 pk;
#pragma unroll
                for (int i = 0; i < 4; ++i)
                    pk[i] = (short)f2b(acc[ms][ns][i] + bb);
                int r = tg0 & 31;                         // window permutation
                int pos = (r < 16) ? (r << 1) : (((r - 16) << 1) + 4);
                int tgp = (tg0 & ~31) + pos;
                *(bf16x4*)(vtb + (((size_t)(bi * 8 + hh) * 64 + j) << 11) + tgp) = pk;
            }
    }
}

// ---------------------------------------------------------------------------
// attn: S^T flash, exp2 domain. Block 256 thr = 4 waves, 64 q per block,
// 4-way key split. Q-tile staged ONCE in LDS (shared by all waves) and
// re-read per g -> qf regs freed; l via scalar rs; VGPR forced <=128
// (launch_bounds(256,4)) for 4 waves/SIMD. Partials merged via a pairwise
// LDS tree (Pa/Pb). Grid swizzled: each XCD sees 4 bh.
// ---------------------------------------------------------------------------
__global__ __launch_bounds__(256, 4)
void attn_kernel(const unsigned short* __restrict__ qb,
                 const unsigned short* __restrict__ kb,
                 const unsigned short* __restrict__ vt,
                 const int* __restrict__ t_self, const int* __restrict__ t_cross,
                 unsigned short* __restrict__ y)
{
    const int bid = blockIdx.x;
    const int bh = ((bid & 7) << 2) | ((bid >> 3) & 3);   // XCD-local bh group
    const int qt = bid >> 5;
    const int b = bh >> 3, h = bh & 7;
    const int tid = threadIdx.x, w = tid >> 6, lane = tid & 63;
    const int quad = lane >> 4, r16 = lane & 15;

    const unsigned short* Q = qb + (size_t)bh * 131072;
    const unsigned short* K = kb + (size_t)bh * 131072;
    const unsigned short* V = vt + (size_t)bh * 131072;
    const int* tsb = t_self + b * 1024;
    const int* tcb = t_cross + b * 1024;

    __shared__ unsigned short Qs[64 * 72];   // 9.2 KB, shared Q tile
    __shared__ unsigned short Pa[64 * 68];   // 8.7 KB, bf16 partial O^T
    __shared__ unsigned short Pb[64 * 68];
    __shared__ float Ls[4][64];

    const int q0 = qt * 64;

    {   // stage Q tile 64x64 (each thread 32 B)
        int row = tid >> 2, c0 = (tid & 3) * 16;
        const unsigned short* s = Q + (size_t)(q0 + row) * 64 + c0;
        bf16x8 v0 = *(const bf16x8*)(s);
        bf16x8 v1 = *(const bf16x8*)(s + 8);
        *(bf16x8*)(Qs + row * 72 + c0) = v0;
        *(bf16x8*)(Qs + row * 72 + c0 + 8) = v1;
    }

    const int* tqp = (qt < 16) ? (tsb + qt * 64) : (tcb + (qt - 16) * 64);
    int tq[4];
#pragma unroll
    for (int g = 0; g < 4; ++g) tq[g] = tqp[g * 16 + r16];

    const f32x4 fz = {0.f, 0.f, 0.f, 0.f};
    f32x4 ot[4][4];
    float rs[4] = {0.f, 0.f, 0.f, 0.f};
#pragma unroll
    for (int g = 0; g < 4; ++g)
#pragma unroll
        for (int nt = 0; nt < 4; ++nt) ot[g][nt] = fz;

    __syncthreads();                          // Qs ready

    for (int it = 0; it < 8; ++it) {
        const int kt = w * 8 + it;
        const int krow = kt * 64;
        const int* tkp = (kt < 16) ? (tsb + krow) : (tcb + krow - 1024);

#pragma unroll
        for (int c = 0; c < 2; ++c) {               // 32-key windows
            const int kw = krow + c * 32;
            i32x4 tk0 = *(const i32x4*)(tkp + c * 32 + quad * 4);
            i32x4 tk1 = *(const i32x4*)(tkp + c * 32 + 16 + quad * 4);
            const unsigned short* kr0 = K + (size_t)(kw + r16) * 64 + quad * 8;
            const unsigned short* kr1 = K + (size_t)(kw + 16 + r16) * 64 + quad * 8;
            bf16x8 ka00 = *(const bf16x8*)(kr0);
            bf16x8 ka01 = *(const bf16x8*)(kr0 + 32);
            bf16x8 ka10 = *(const bf16x8*)(kr1);
            bf16x8 ka11 = *(const bf16x8*)(kr1 + 32);

            bf16x8 pf[4];
#pragma unroll
            for (int g = 0; g < 4; ++g) {
                bf16x8 qg0 = *(const bf16x8*)(Qs + (g * 16 + r16) * 72 + quad * 8);
                bf16x8 qg1 = *(const bf16x8*)(Qs + (g * 16 + r16) * 72 + 32 + quad * 8);
                f32x4 s0 = fz, s1 = fz;
                s0 = __builtin_amdgcn_mfma_f32_16x16x32_bf16(ka00, qg0, s0, 0, 0, 0);
                s0 = __builtin_amdgcn_mfma_f32_16x16x32_bf16(ka01, qg1, s0, 0, 0, 0);
                s1 = __builtin_amdgcn_mfma_f32_16x16x32_bf16(ka10, qg0, s1, 0, 0, 0);
                s1 = __builtin_amdgcn_mfma_f32_16x16x32_bf16(ka11, qg1, s1, 0, 0, 0);
                float e[8];
#pragma unroll
                for (int i = 0; i < 4; ++i) {
                    float a0 = (tq[g] >= tk0[i]) ? s0[i] : -1e9f;   // select ARG
                    float a1 = (tq[g] >= tk1[i]) ? s1[i] : -1e9f;
                    e[i]     = __builtin_amdgcn_exp2f(a0);
                    e[4 + i] = __builtin_amdgcn_exp2f(a1);
                }
                rs[g] += ((e[0] + e[1]) + (e[2] + e[3]))
                       + ((e[4] + e[5]) + (e[6] + e[7]));
                union { unsigned int d[4]; bf16x8 v; } pu;          // truncate-pack
                pu.d[0] = __builtin_amdgcn_perm(fbits(e[1]), fbits(e[0]), 0x07060302u);
                pu.d[1] = __builtin_amdgcn_perm(fbits(e[3]), fbits(e[2]), 0x07060302u);
                pu.d[2] = __builtin_amdgcn_perm(fbits(e[5]), fbits(e[4]), 0x07060302u);
                pu.d[3] = __builtin_amdgcn_perm(fbits(e[7]), fbits(e[6]), 0x07060302u);
                pf[g] = pu.v;
            }

            // O^T += V^T · P^T  (K=32, b128 V loads from permuted layout)
#pragma unroll
            for (int nt = 0; nt < 4; ++nt) {
                bf16x8 va = *(const bf16x8*)(V + (size_t)(nt * 16 + r16) * 2048
                                               + kw + quad * 8);
                ot[0][nt] = __builtin_amdgcn_mfma_f32_16x16x32_bf16(va, pf[0], ot[0][nt], 0, 0, 0);
                ot[1][nt] = __builtin_amdgcn_mfma_f32_16x16x32_bf16(va, pf[1], ot[1][nt], 0, 0, 0);
                ot[2][nt] = __builtin_amdgcn_mfma_f32_16x16x32_bf16(va, pf[2], ot[2][nt], 0, 0, 0);
                ot[3][nt] = __builtin_amdgcn_mfma_f32_16x16x32_bf16(va, pf[3], ot[3][nt], 0, 0, 0);
            }
        }
    }

    // l partial: reduce across quads, publish
#pragma unroll
    for (int g = 0; g < 4; ++g) {
        rs[g] += __shfl_xor(rs[g], 16);
        rs[g] += __shfl_xor(rs[g], 32);
    }
    if (quad == 0) {
#pragma unroll
        for (int g = 0; g < 4; ++g) Ls[w][g * 16 + r16] = rs[g];
    }

    // pairwise tree merge: (0+1) and (2+3) via Pa/Pb, then 0 + (2+3) via Pa
    unsigned short* wbuf = (w == 1) ? Pa : Pb;
    if (w == 1 || w == 3) {
#pragma unroll
        for (int g = 0; g < 4; ++g)
#pragma unroll
            for (int nt = 0; nt < 4; ++nt) {
                union { unsigned int u[2]; bf16x4 v; } pk;
                pk.u[0] = (unsigned int)f2b(ot[g][nt][0]) | ((unsigned int)f2b(ot[g][nt][1]) << 16);
                pk.u[1] = (unsigned int)f2b(ot[g][nt][2]) | ((unsigned int)f2b(ot[g][nt][3]) << 16);
                *(bf16x4*)(wbuf + (g * 16 + r16) * 68 + nt * 16 + quad * 4) = pk.v;
            }
    }
    __syncthreads();
    if (w == 0 || w == 2) {
        const unsigned short* rbuf = (w == 0) ? Pa : Pb;
#pragma unroll
        for (int g = 0; g < 4; ++g)
#pragma unroll
            for (int nt = 0; nt < 4; ++nt) {
                bf16x4 v = *(const bf16x4*)(rbuf + (g * 16 + r16) * 68 + nt * 16 + quad * 4);
#pragma unroll
                for (int i = 0; i < 4; ++i)
                    ot[g][nt][i] += b2f(((const unsigned short*)&v)[i]);
            }
    }
    __syncthreads();
    if (w == 2) {
#pragma unroll
        for (int g = 0; g < 4; ++g)
#pragma unroll
            for (int nt = 0; nt < 4; ++nt) {
                union { unsigned int u[2]; bf16x4 v; } pk;
                pk.u[0] = (unsigned int)f2b(ot[g][nt][0]) | ((unsigned int)f2b(ot[g][nt][1]) << 16);
                pk.u[1] = (unsigned int)f2b(ot[g][nt][2]) | ((unsigned int)f2b(ot[g][nt][3]) << 16);
                *(bf16x4*)(Pa + (g * 16 + r16) * 68 + nt * 16 + quad * 4) = pk.v;
            }
    }
    __syncthreads();
    if (w == 0) {
        float l[4];
#pragma unroll
        for (int g = 0; g < 4; ++g)
            l[g] = Ls[0][g * 16 + r16] + Ls[1][g * 16 + r16]
                 + Ls[2][g * 16 + r16] + Ls[3][g * 16 + r16];
#pragma unroll
        for (int g = 0; g < 4; ++g) {
            float inv = (l[g] > 0.f) ? (1.f / l[g]) : 0.f;
            unsigned short* yr = y + (((size_t)(b * 2048 + q0 + g * 16 + r16)) << 9) + h * 64;
#pragma unroll
            for (int nt = 0; nt < 4; ++nt) {
                bf16x4 v = *(const bf16x4*)(Pa + (g * 16 + r16) * 68 + nt * 16 + quad * 4);
                bf16x4 pk;
#pragma unroll
                for (int i = 0; i < 4; ++i)
                    pk[i] = (short)f2b((ot[g][nt][i] + b2f(((const unsigned short*)&v)[i])) * inv);
                *(bf16x4*)(yr + nt * 16 + quad * 4) = pk;
            }
        }
    }
}

// ---------------------------------------------------------------------------
// proj: Y(8192x512 bf16) @ wtp^T + b -> fp32 out (tuple split). Operand-
// swapped MFMA -> each lane holds 4 consecutive n at one t -> dwordx4 stores.
// ---------------------------------------------------------------------------
__global__ __launch_bounds__(256)
void proj_kernel(const unsigned short* __restrict__ X,
                 const unsigned short* __restrict__ Wt,
                 const float* __restrict__ bias,
                 float* __restrict__ out)
{
    const int m0 = blockIdx.x * 128, n0 = blockIdx.y * 128;
    __shared__ unsigned short As[128 * 32];
    __shared__ unsigned short Bs[128 * 32];

    const int tid = threadIdx.x, lane = tid & 63, w = tid >> 6;
    const int quad = lane >> 4, r16 = lane & 15;
    const int mrow = (w >> 1) * 64, ncol = (w & 1) * 64;

    const f32x4 fz = {0.f, 0.f, 0.f, 0.f};
    f32x4 acc[4][4];
#pragma unroll
    for (int a = 0; a < 4; ++a)
#pragma unroll
        for (int b = 0; b < 4; ++b) acc[a][b] = fz;

    const int ci   = w << 1;
    const int rofs = lane >> 2, kofs = (lane & 3) * 8;
    const unsigned short* gA = X + (size_t)(m0 + ci * 16 + rofs) * 512 + kofs;
    const unsigned short* gB = Wt + (size_t)(n0 + ci * 16 + rofs) * 512 + kofs;
    unsigned short* lA = As + ci * 512 + lane * 8;
    unsigned short* lB = Bs + ci * 512 + lane * 8;

    for (int k0 = 0; k0 < 512; k0 += 32) {
        glds16(gA + k0, lA);
        glds16(gA + 16 * 512 + k0, lA + 512);
        glds16(gB + k0, lB);
        glds16(gB + 16 * 512 + k0, lB + 512);
        __syncthreads();

        bf16x8 af[4], bfr[4];
#pragma unroll
        for (int ms = 0; ms < 4; ++ms)
            af[ms] = *(const bf16x8*)(As + (mrow + ms * 16 + r16) * 32 + quad * 8);
#pragma unroll
        for (int ns = 0; ns < 4; ++ns)
            bfr[ns] = *(const bf16x8*)(Bs + (ncol + ns * 16 + r16) * 32 + quad * 8);
#pragma unroll
        for (int a = 0; a < 4; ++a)
#pragma unroll
            for (int b = 0; b < 4; ++b)
                acc[a][b] = __builtin_amdgcn_mfma_f32_16x16x32_bf16(
                    bfr[a], af[b], acc[a][b], 0, 0, 0);       // C = [n][t]
        __syncthreads();
    }

#pragma unroll
    for (int ws = 0; ws < 4; ++ws) {
        int nb = n0 + ncol + ws * 16 + quad * 4;
        f32x4 bb = *(const f32x4*)(bias + nb);
#pragma unroll
        for (int xs = 0; xs < 4; ++xs) {
            int m = m0 + mrow + xs * 16 + r16;
            int bi = m >> 11, t = m & 2047;
            f32x4 v;
#pragma unroll
            for (int i = 0; i < 4; ++i) v[i] = acc[ws][xs][i] + bb[i];
            size_t idx = (t < 1024)
                ? ((size_t)bi * 1024 + t) * 512 + nb
                : (size_t)2097152 + ((size_t)bi * 1024 + (t - 1024)) * 512 + nb;
            *(f32x4*)(out + idx) = v;
        }
    }
}

// ---------------------------------------------------------------------------
extern "C" void kernel_launch(void* const* d_in, const int* in_sizes, int n_in,
                              void* d_out, int out_size, void* d_ws, size_t ws_size,
                              hipStream_t stream)
{
    const float* self_seq  = (const float*)d_in[0];
    const float* cross_seq = (const float*)d_in[1];
    const int*   t_self    = (const int*)d_in[2];
    const int*   t_cross   = (const int*)d_in[3];
    const float* W_self    = (const float*)d_in[4];
    const float* b_self    = (const float*)d_in[5];
    const float* W_cross   = (const float*)d_in[6];
    const float* b_cross   = (const float*)d_in[7];
    const float* W_proj    = (const float*)d_in[8];
    const float* b_proj    = (const float*)d_in[9];
    float* out = (float*)d_out;

    // ws (32 MB): q, k, vt, y. d_out slack holds xb/wt/wtp until proj.
    unsigned short* qbuf = (unsigned short*)d_ws;
    unsigned short* kbuf = qbuf + 4194304;
    unsigned short* vtb  = kbuf + 4194304;
    unsigned short* ybuf = vtb + 4194304;
    unsigned short* xb   = (unsigned short*)d_out;
    unsigned short* wt   = xb + 4194304;
    unsigned short* wtp  = wt + 1572864;

    prep_kernel<<<dim3(2496), 256, 0, stream>>>(
        self_seq, cross_seq, W_self, W_cross, W_proj, xb, wt, wtp);

    qkv_kernel<<<dim3(32, 12, 2), 256, 0, stream>>>(
        xb, wt, b_self, b_cross, qbuf, kbuf, vtb);

    attn_kernel<<<dim3(1024), 256, 0, stream>>>(
        qbuf, kbuf, vtb, t_self, t_cross, ybuf);

    proj_kernel<<<dim3(64, 4), 256, 0, stream>>>(
        ybuf, wtp, b_proj, out);
}

// Round 10
// 212.853 us; speedup vs baseline: 2.5470x; 2.5470x over previous
//
#include <hip/hip_runtime.h>

// ---------------------------------------------------------------------------
// SelfCrossAttention: B=4, T=1024+1024, d=512, H=8, hd=64. fp32 I/O,
// bf16 MFMA internals.
// prep (X->bf16; W_self/W_cross -> wt[n][k], q section pre-scaled by
//       0.125*log2(e); W_proj -> wtp[n][k])
//   -> qkv (128x128 glds GEMM; q/k computed TRANSPOSED via operand swap so
//           stores are b64-coalesced; V stored transposed+window-permuted)
//   -> attn (R8 structure: S^T flash, 64q/wave, 4-way key split, exp2
//            softmax, l via ones-A MFMA, natural VGPR allocation — DO NOT
//            cap VGPR: launch_bounds(256,4) caused accumulator spills,
//            780 MB scratch traffic, 5x regression in R9)
//   -> proj (glds GEMM, operand-swapped -> dwordx4 stores, tuple split).
// ---------------------------------------------------------------------------

typedef short     bf16x8 __attribute__((ext_vector_type(8)));
typedef short     bf16x4 __attribute__((ext_vector_type(4)));
typedef float     f32x4  __attribute__((ext_vector_type(4)));
typedef int       i32x4  __attribute__((ext_vector_type(4)));

#define DI __device__ __forceinline__

DI unsigned short f2b(float f) {            // fp32 -> bf16 bits, RNE-ish
    union { float f; unsigned int u; } x; x.f = f;
    unsigned int r = x.u + 0x7fffu + ((x.u >> 16) & 1u);
    return (unsigned short)(r >> 16);
}
DI unsigned int fbits(float f) { union { float f; unsigned int u; } x; x.f = f; return x.u; }
DI float bitsf(unsigned int u) { union { unsigned int u; float f; } x; x.u = u; return x.f; }
DI float b2f(unsigned short v) { return bitsf(((unsigned int)v) << 16); }

DI void glds16(const unsigned short* g, unsigned short* l) {   // 16B global->LDS
    __builtin_amdgcn_global_load_lds(
        (const __attribute__((address_space(1))) void*)g,
        (__attribute__((address_space(3))) void*)l, 16, 0, 0);
}

#define QSCALE 0.18033688011112042f   // 0.125 * log2(e): exp2-domain scores

// ---------------------------------------------------------------------------
// prep: [0,2048): X fp32 -> bf16 flat.
//       [2048,2432): W_self/W_cross -> wt[src][n][k], q-section * QSCALE
//       [2432,2496): W_proj -> wtp[n][k]
// ---------------------------------------------------------------------------
__global__ __launch_bounds__(256)
void prep_kernel(const float* __restrict__ Xs, const float* __restrict__ Xc,
                 const float* __restrict__ Ws, const float* __restrict__ Wc,
                 const float* __restrict__ Wp,
                 unsigned short* __restrict__ xb, unsigned short* __restrict__ wt,
                 unsigned short* __restrict__ wtp)
{
    const int bid = blockIdx.x, tid = threadIdx.x;
    if (bid < 2048) {
        int idx = bid * 2048 + tid * 8;
        const float* s = (idx < 2097152) ? (Xs + idx) : (Xc + idx - 2097152);
        f32x4 a0 = *(const f32x4*)s;
        f32x4 a1 = *(const f32x4*)(s + 4);
        bf16x8 v;
#pragma unroll
        for (int j = 0; j < 4; ++j) {
            ((unsigned short*)&v)[j]     = f2b(a0[j]);
            ((unsigned short*)&v)[4 + j] = f2b(a1[j]);
        }
        *(bf16x8*)(xb + idx) = v;
        return;
    }
    __shared__ unsigned short Tt[64 * 72];
    const float* W;
    unsigned short* dst;
    int k0, n0, ldn;
    float sc = 1.0f;
    if (bid < 2432) {
        int tj  = bid - 2048;
        int src = tj >= 192;  tj -= src * 192;
        k0  = (tj / 24) * 64;
        n0  = (tj % 24) * 64;
        W   = src ? Wc : Ws;
        ldn = 1536;
        dst = wt + (size_t)src * 786432;
        if (n0 < 512) sc = QSCALE;
    } else {
        int tj = bid - 2432;
        k0  = (tj >> 3) * 64;
        n0  = (tj & 7) * 64;
        W   = Wp;
        ldn = 512;
        dst = wtp;
    }
#pragma unroll
    for (int r = 0; r < 4; ++r) {
        int g  = tid + r * 256;
        int kr = g >> 4, nc4 = (g & 15) * 4;
        f32x4 v = *(const f32x4*)(W + (size_t)(k0 + kr) * ldn + n0 + nc4);
#pragma unroll
        for (int u = 0; u < 4; ++u)
            Tt[(nc4 + u) * 72 + kr] = f2b(v[u] * sc);
    }
    __syncthreads();
#pragma unroll
    for (int r = 0; r < 2; ++r) {
        int c = tid + r * 256;
        int nl = c >> 3, k8 = (c & 7) * 8;
        *(bf16x8*)(dst + (size_t)(n0 + nl) * 512 + k0 + k8) =
            *(const bf16x8*)(Tt + nl * 72 + k8);
    }
}

// ---------------------------------------------------------------------------
// QKV: xb @ wt^T + bias. 128x128 tile, glds staging. For q/k n-blocks the
// MFMA operands are SWAPPED (C comes out [n][t]) so each lane holds 4
// consecutive j at one t -> b64 stores. V blocks keep original orientation
// and store transposed+window-permuted (b64).
// ---------------------------------------------------------------------------
__global__ __launch_bounds__(256)
void qkv_kernel(const unsigned short* __restrict__ xb,
                const unsigned short* __restrict__ wt,
                const float* __restrict__ bs, const float* __restrict__ bc,
                unsigned short* __restrict__ qb, unsigned short* __restrict__ kb,
                unsigned short* __restrict__ vtb)
{
    const int src = blockIdx.z;
    const int m0 = blockIdx.x * 128, n0 = blockIdx.y * 128;
    const float* bias = src ? bc : bs;
    const unsigned short* X = xb + (size_t)src * 2097152;
    const unsigned short* W = wt + (size_t)src * 786432;

    __shared__ unsigned short As[128 * 32];
    __shared__ unsigned short Bs[128 * 32];

    const int tid = threadIdx.x, lane = tid & 63, w = tid >> 6;
    const int quad = lane >> 4, r16 = lane & 15;
    const int mrow = (w >> 1) * 64, ncol = (w & 1) * 64;
    const bool qk = (n0 < 1024);

    const f32x4 fz = {0.f, 0.f, 0.f, 0.f};
    f32x4 acc[4][4];
#pragma unroll
    for (int a = 0; a < 4; ++a)
#pragma unroll
        for (int b = 0; b < 4; ++b) acc[a][b] = fz;

    const int ci   = w << 1;
    const int rofs = lane >> 2, kofs = (lane & 3) * 8;
    const unsigned short* gA = X + (size_t)(m0 + ci * 16 + rofs) * 512 + kofs;
    const unsigned short* gB = W + (size_t)(n0 + ci * 16 + rofs) * 512 + kofs;
    unsigned short* lA = As + ci * 512 + lane * 8;
    unsigned short* lB = Bs + ci * 512 + lane * 8;

    for (int k0 = 0; k0 < 512; k0 += 32) {
        glds16(gA + k0, lA);
        glds16(gA + 16 * 512 + k0, lA + 512);
        glds16(gB + k0, lB);
        glds16(gB + 16 * 512 + k0, lB + 512);
        __syncthreads();

        bf16x8 af[4], bfr[4];
#pragma unroll
        for (int ms = 0; ms < 4; ++ms)
            af[ms] = *(const bf16x8*)(As + (mrow + ms * 16 + r16) * 32 + quad * 8);
#pragma unroll
        for (int ns = 0; ns < 4; ++ns)
            bfr[ns] = *(const bf16x8*)(Bs + (ncol + ns * 16 + r16) * 32 + quad * 8);
        if (qk) {
#pragma unroll
            for (int a = 0; a < 4; ++a)
#pragma unroll
                for (int b = 0; b < 4; ++b)
                    acc[a][b] = __builtin_amdgcn_mfma_f32_16x16x32_bf16(
                        bfr[a], af[b], acc[a][b], 0, 0, 0);   // C = [n][t]
        } else {
#pragma unroll
            for (int a = 0; a < 4; ++a)
#pragma unroll
                for (int b = 0; b < 4; ++b)
                    acc[a][b] = __builtin_amdgcn_mfma_f32_16x16x32_bf16(
                        af[a], bfr[b], acc[a][b], 0, 0, 0);   // C = [t][n]
        }
        __syncthreads();
    }

    if (qk) {
        const bool isq = (n0 < 512);
        unsigned short* dst = isq ? qb : kb;
        const float bsc = isq ? QSCALE : 1.0f;
#pragma unroll
        for (int ws = 0; ws < 4; ++ws) {
            int nb = n0 + ncol + ws * 16 + quad * 4;      // 4 consecutive n
            f32x4 bb = *(const f32x4*)(bias + nb);
            int col = nb & 511, hh = col >> 6, j0 = col & 63;
#pragma unroll
            for (int xs = 0; xs < 4; ++xs) {
                int mb = m0 + mrow + xs * 16 + r16;
                int bi = mb >> 10, tg = (mb & 1023) + (src << 10);
                bf16x4 pk;
#pragma unroll
                for (int i = 0; i < 4; ++i)
                    pk[i] = (short)f2b(acc[ws][xs][i] + bb[i] * bsc);
                *(bf16x4*)(dst + (((size_t)(bi * 8 + hh) * 2048 + tg) << 6) + j0) = pk;
            }
        }
    } else {
#pragma unroll
        for (int ms = 0; ms < 4; ++ms)
#pragma unroll
            for (int ns = 0; ns < 4; ++ns) {
                int n = n0 + ncol + ns * 16 + r16;
                int col = n & 511, hh = col >> 6, j = col & 63;
                float bb = bias[n];
                int mb = m0 + mrow + ms * 16 + quad * 4;
                int bi = mb >> 10, tg0 = (mb & 1023) + (src << 10);
                bf16x4 pk;
#pragma unroll
                for (int i = 0; i < 4; ++i)
                    pk[i] = (short)f2b(acc[ms][ns][i] + bb);
                int r = tg0 & 31;                         // window permutation
                int pos = (r < 16) ? (r << 1) : (((r - 16) << 1) + 4);
                int tgp = (tg0 & ~31) + pos;
                *(bf16x4*)(vtb + (((size_t)(bi * 8 + hh) * 64 + j) << 11) + tgp) = pk;
            }
    }
}

// ---------------------------------------------------------------------------
// attn (R8 structure, natural VGPR): S^T flash, exp2 domain. Block 256 thr =
// 4 waves; block = 64 queries of one bh; wave = all 64 q x 8 K-tiles (4-way
// key split). Per 32-key window: two S-tiles -> exp2 -> perm-pack
// (truncating) -> K=32 PV; l summed by ones-A MFMA from the same packed P.
// Grid swizzled: each XCD sees 4 bh.
// ---------------------------------------------------------------------------
__global__ __launch_bounds__(256)
void attn_kernel(const unsigned short* __restrict__ qb,
                 const unsigned short* __restrict__ kb,
                 const unsigned short* __restrict__ vt,
                 const int* __restrict__ t_self, const int* __restrict__ t_cross,
                 unsigned short* __restrict__ y)
{
    const int bid = blockIdx.x;
    const int bh = ((bid & 7) << 2) | ((bid >> 3) & 3);   // XCD-local bh group
    const int qt = bid >> 5;
    const int b = bh >> 3, h = bh & 7;
    const int tid = threadIdx.x, ksplit = tid >> 6, lane = tid & 63;
    const int quad = lane >> 4, r16 = lane & 15;

    const unsigned short* Q = qb + (size_t)bh * 131072;
    const unsigned short* K = kb + (size_t)bh * 131072;
    const unsigned short* V = vt + (size_t)bh * 131072;
    const int* tsb = t_self + b * 1024;
    const int* tcb = t_cross + b * 1024;

    __shared__ unsigned short Op[4][64 * 68];   // bf16 partial O^T per split
    __shared__ float Ls[4][64];

    const int q0 = qt * 64;

    bf16x8 qf[4][2];
#pragma unroll
    for (int g = 0; g < 4; ++g)
#pragma unroll
        for (int ks = 0; ks < 2; ++ks)
            qf[g][ks] = *(const bf16x8*)(Q + (size_t)(q0 + g * 16 + r16) * 64
                                           + ks * 32 + quad * 8);

    const int* tqp = (qt < 16) ? (tsb + qt * 64) : (tcb + (qt - 16) * 64);
    int tq[4];
#pragma unroll
    for (int g = 0; g < 4; ++g) tq[g] = tqp[g * 16 + r16];

    const f32x4 fz = {0.f, 0.f, 0.f, 0.f};
    f32x4 ot[4][4], al[4];
#pragma unroll
    for (int g = 0; g < 4; ++g) {
        al[g] = fz;
#pragma unroll
        for (int nt = 0; nt < 4; ++nt) ot[g][nt] = fz;
    }
    const bf16x8 ones = {(short)0x3F80, (short)0x3F80, (short)0x3F80, (short)0x3F80,
                         (short)0x3F80, (short)0x3F80, (short)0x3F80, (short)0x3F80};

    for (int it = 0; it < 8; ++it) {
        const int kt = ksplit * 8 + it;
        const int krow = kt * 64;
        const int* tkp = (kt < 16) ? (tsb + krow) : (tcb + krow - 1024);

#pragma unroll
        for (int c = 0; c < 2; ++c) {               // 32-key windows
            const int kw = krow + c * 32;
            i32x4 tk0 = *(const i32x4*)(tkp + c * 32 + quad * 4);
            i32x4 tk1 = *(const i32x4*)(tkp + c * 32 + 16 + quad * 4);
            const unsigned short* kr0 = K + (size_t)(kw + r16) * 64 + quad * 8;
            const unsigned short* kr1 = K + (size_t)(kw + 16 + r16) * 64 + quad * 8;
            bf16x8 ka00 = *(const bf16x8*)(kr0);
            bf16x8 ka01 = *(const bf16x8*)(kr0 + 32);
            bf16x8 ka10 = *(const bf16x8*)(kr1);
            bf16x8 ka11 = *(const bf16x8*)(kr1 + 32);

            bf16x8 pf[4];
#pragma unroll
            for (int g = 0; g < 4; ++g) {
                f32x4 s0 = fz, s1 = fz;
                s0 = __builtin_amdgcn_mfma_f32_16x16x32_bf16(ka00, qf[g][0], s0, 0, 0, 0);
                s0 = __builtin_amdgcn_mfma_f32_16x16x32_bf16(ka01, qf[g][1], s0, 0, 0, 0);
                s1 = __builtin_amdgcn_mfma_f32_16x16x32_bf16(ka10, qf[g][0], s1, 0, 0, 0);
                s1 = __builtin_amdgcn_mfma_f32_16x16x32_bf16(ka11, qf[g][1], s1, 0, 0, 0);
                float e[8];
#pragma unroll
                for (int i = 0; i < 4; ++i) {
                    float a0 = (tq[g] >= tk0[i]) ? s0[i] : -1e9f;   // select ARG
                    float a1 = (tq[g] >= tk1[i]) ? s1[i] : -1e9f;
                    e[i]     = __builtin_amdgcn_exp2f(a0);          // exp2 domain
                    e[4 + i] = __builtin_amdgcn_exp2f(a1);
                }
                union { unsigned int d[4]; bf16x8 v; } pu;          // truncate-pack
                pu.d[0] = __builtin_amdgcn_perm(fbits(e[1]), fbits(e[0]), 0x07060302u);
                pu.d[1] = __builtin_amdgcn_perm(fbits(e[3]), fbits(e[2]), 0x07060302u);
                pu.d[2] = __builtin_amdgcn_perm(fbits(e[5]), fbits(e[4]), 0x07060302u);
                pu.d[3] = __builtin_amdgcn_perm(fbits(e[7]), fbits(e[6]), 0x07060302u);
                pf[g] = pu.v;
                // l partial from the SAME stored-precision P (ones-A MFMA)
                al[g] = __builtin_amdgcn_mfma_f32_16x16x32_bf16(ones, pf[g], al[g], 0, 0, 0);
            }

            // O^T += V^T · P^T  (K=32, b128 V loads from permuted layout)
#pragma unroll
            for (int nt = 0; nt < 4; ++nt) {
                bf16x8 va = *(const bf16x8*)(V + (size_t)(nt * 16 + r16) * 2048
                                               + kw + quad * 8);
                ot[0][nt] = __builtin_amdgcn_mfma_f32_16x16x32_bf16(va, pf[0], ot[0][nt], 0, 0, 0);
                ot[1][nt] = __builtin_amdgcn_mfma_f32_16x16x32_bf16(va, pf[1], ot[1][nt], 0, 0, 0);
                ot[2][nt] = __builtin_amdgcn_mfma_f32_16x16x32_bf16(va, pf[2], ot[2][nt], 0, 0, 0);
                ot[3][nt] = __builtin_amdgcn_mfma_f32_16x16x32_bf16(va, pf[3], ot[3][nt], 0, 0, 0);
            }
        }
    }

    // write partials (bf16 O^T, fp32 l) and merge
    unsigned short* opw = Op[ksplit];
#pragma unroll
    for (int g = 0; g < 4; ++g)
#pragma unroll
        for (int nt = 0; nt < 4; ++nt) {
            union { unsigned int u[2]; bf16x4 v; } pk;
            pk.u[0] = (unsigned int)f2b(ot[g][nt][0]) | ((unsigned int)f2b(ot[g][nt][1]) << 16);
            pk.u[1] = (unsigned int)f2b(ot[g][nt][2]) | ((unsigned int)f2b(ot[g][nt][3]) << 16);
            *(bf16x4*)(opw + (g * 16 + r16) * 68 + nt * 16 + quad * 4) = pk.v;
        }
    if (quad == 0) {
#pragma unroll
        for (int g = 0; g < 4; ++g) Ls[ksplit][g * 16 + r16] = al[g][0];
    }
    __syncthreads();

    for (int c = tid; c < 1024; c += 256) {
        int q = c >> 4, j4 = (c & 15) * 4;
        float l = Ls[0][q] + Ls[1][q] + Ls[2][q] + Ls[3][q];
        float inv = (l > 0.f) ? (1.f / l) : 0.f;
        float s[4] = {0.f, 0.f, 0.f, 0.f};
#pragma unroll
        for (int sp = 0; sp < 4; ++sp) {
            bf16x4 v = *(const bf16x4*)(Op[sp] + q * 68 + j4);
#pragma unroll
            for (int i = 0; i < 4; ++i)
                s[i] += b2f(((const unsigned short*)&v)[i]);
        }
        bf16x4 pk;
#pragma unroll
        for (int i = 0; i < 4; ++i) pk[i] = (short)f2b(s[i] * inv);
        *(bf16x4*)(y + (((size_t)(b * 2048 + q0 + q)) << 9) + h * 64 + j4) = pk;
    }
}

// ---------------------------------------------------------------------------
// proj: Y(8192x512 bf16) @ wtp^T + b -> fp32 out (tuple split). Operand-
// swapped MFMA -> each lane holds 4 consecutive n at one t -> dwordx4 stores.
// ---------------------------------------------------------------------------
__global__ __launch_bounds__(256)
void proj_kernel(const unsigned short* __restrict__ X,
                 const unsigned short* __restrict__ Wt,
                 const float* __restrict__ bias,
                 float* __restrict__ out)
{
    const int m0 = blockIdx.x * 128, n0 = blockIdx.y * 128;
    __shared__ unsigned short As[128 * 32];
    __shared__ unsigned short Bs[128 * 32];

    const int tid = threadIdx.x, lane = tid & 63, w = tid >> 6;
    const int quad = lane >> 4, r16 = lane & 15;
    const int mrow = (w >> 1) * 64, ncol = (w & 1) * 64;

    const f32x4 fz = {0.f, 0.f, 0.f, 0.f};
    f32x4 acc[4][4];
#pragma unroll
    for (int a = 0; a < 4; ++a)
#pragma unroll
        for (int b = 0; b < 4; ++b) acc[a][b] = fz;

    const int ci   = w << 1;
    const int rofs = lane >> 2, kofs = (lane & 3) * 8;
    const unsigned short* gA = X + (size_t)(m0 + ci * 16 + rofs) * 512 + kofs;
    const unsigned short* gB = Wt + (size_t)(n0 + ci * 16 + rofs) * 512 + kofs;
    unsigned short* lA = As + ci * 512 + lane * 8;
    unsigned short* lB = Bs + ci * 512 + lane * 8;

    for (int k0 = 0; k0 < 512; k0 += 32) {
        glds16(gA + k0, lA);
        glds16(gA + 16 * 512 + k0, lA + 512);
        glds16(gB + k0, lB);
        glds16(gB + 16 * 512 + k0, lB + 512);
        __syncthreads();

        bf16x8 af[4], bfr[4];
#pragma unroll
        for (int ms = 0; ms < 4; ++ms)
            af[ms] = *(const bf16x8*)(As + (mrow + ms * 16 + r16) * 32 + quad * 8);
#pragma unroll
        for (int ns = 0; ns < 4; ++ns)
            bfr[ns] = *(const bf16x8*)(Bs + (ncol + ns * 16 + r16) * 32 + quad * 8);
#pragma unroll
        for (int a = 0; a < 4; ++a)
#pragma unroll
            for (int b = 0; b < 4; ++b)
                acc[a][b] = __builtin_amdgcn_mfma_f32_16x16x32_bf16(
                    bfr[a], af[b], acc[a][b], 0, 0, 0);       // C = [n][t]
        __syncthreads();
    }

#pragma unroll
    for (int ws = 0; ws < 4; ++ws) {
        int nb = n0 + ncol + ws * 16 + quad * 4;
        f32x4 bb = *(const f32x4*)(bias + nb);
#pragma unroll
        for (int xs = 0; xs < 4; ++xs) {
            int m = m0 + mrow + xs * 16 + r16;
            int bi = m >> 11, t = m & 2047;
            f32x4 v;
#pragma unroll
            for (int i = 0; i < 4; ++i) v[i] = acc[ws][xs][i] + bb[i];
            size_t idx = (t < 1024)
                ? ((size_t)bi * 1024 + t) * 512 + nb
                : (size_t)2097152 + ((size_t)bi * 1024 + (t - 1024)) * 512 + nb;
            *(f32x4*)(out + idx) = v;
        }
    }
}

// ---------------------------------------------------------------------------
extern "C" void kernel_launch(void* const* d_in, const int* in_sizes, int n_in,
                              void* d_out, int out_size, void* d_ws, size_t ws_size,
                              hipStream_t stream)
{
    const float* self_seq  = (const float*)d_in[0];
    const float* cross_seq = (const float*)d_in[1];
    const int*   t_self    = (const int*)d_in[2];
    const int*   t_cross   = (const int*)d_in[3];
    const float* W_self    = (const float*)d_in[4];
    const float* b_self    = (const float*)d_in[5];
    const float* W_cross   = (const float*)d_in[6];
    const float* b_cross   = (const float*)d_in[7];
    const float* W_proj    = (const float*)d_in[8];
    const float* b_proj    = (const float*)d_in[9];
    float* out = (float*)d_out;

    // ws (32 MB): q, k, vt, y. d_out slack holds xb/wt/wtp until proj.
    unsigned short* qbuf = (unsigned short*)d_ws;
    unsigned short* kbuf = qbuf + 4194304;
    unsigned short* vtb  = kbuf + 4194304;
    unsigned short* ybuf = vtb + 4194304;
    unsigned short* xb   = (unsigned short*)d_out;
    unsigned short* wt   = xb + 4194304;
    unsigned short* wtp  = wt + 1572864;

    prep_kernel<<<dim3(2496), 256, 0, stream>>>(
        self_seq, cross_seq, W_self, W_cross, W_proj, xb, wt, wtp);

    qkv_kernel<<<dim3(32, 12, 2), 256, 0, stream>>>(
        xb, wt, b_self, b_cross, qbuf, kbuf, vtb);

    attn_kernel<<<dim3(1024), 256, 0, stream>>>(
        qbuf, kbuf, vtb, t_self, t_cross, ybuf);

    proj_kernel<<<dim3(64, 4), 256, 0, stream>>>(
        ybuf, wtp, b_proj, out);
}